// Round 1
// baseline (9007.587 us; speedup 1.0000x reference)
//
#include <hip/hip_runtime.h>
#include <hip/hip_bf16.h>
#include <stdint.h>

#define TT 4096
#define EE 256
#define HH 256
#define G4 1024
#define LL 20
#define STARTT 18
#define STOPP 19
#define NEGV -10000.0f
#define NCH 256   // TT/16

typedef short v8s __attribute__((ext_vector_type(8)));
typedef float v4f __attribute__((ext_vector_type(4)));
typedef _Float16 h2 __attribute__((ext_vector_type(2)));
typedef float f2v __attribute__((ext_vector_type(2)));

// ---------- helpers ----------
__device__ inline float bf2f(unsigned short u){
  unsigned int x = ((unsigned int)u) << 16;
  return __builtin_bit_cast(float, x);
}
__device__ inline unsigned short f2bf(float f){
  unsigned int x = __builtin_bit_cast(unsigned int, f);
  unsigned int r = (x + 0x7FFFu + ((x >> 16) & 1u)) >> 16;
  return (unsigned short)r;
}
__device__ inline h2 as_h2(unsigned int v){ return __builtin_bit_cast(h2, v); }

#if __has_builtin(__builtin_amdgcn_fdot2)
#define FDOT2(a,b,c) __builtin_amdgcn_fdot2((a),(b),(c),false)
#else
__device__ inline float fdot2_sw(h2 a, h2 b, float c){
  return c + (float)a.x*(float)b.x + (float)a.y*(float)b.y;
}
#define FDOT2(a,b,c) fdot2_sw((a),(b),(c))
#endif

// manual OCP e4m3fn encode (prep path only; round-half-up is fine here)
__device__ inline unsigned char f2e4m3(float x){
  unsigned int b = __builtin_bit_cast(unsigned int, x);
  unsigned int s = (b >> 24) & 0x80u;
  float a = fabsf(x);
  if (!(a > 0.f)) return (unsigned char)s;
  if (a >= 448.f) return (unsigned char)(s | 0x7E);
  int e = (int)((b >> 23) & 0xFF) - 127;
  if (e < -6){
    int m = (int)(a * 512.f + 0.5f);
    if (m > 7) m = 7;
    return (unsigned char)(s | m);
  }
  unsigned int m23 = b & 0x7FFFFFu;
  unsigned int m3 = (m23 + 0x80000u) >> 20;
  int ee = e + 7;
  if (m3 == 8){ m3 = 0; ee++; }
  if (ee > 15) return (unsigned char)(s | 0x7E);
  return (unsigned char)(s | ((unsigned)ee << 3) | m3);
}

#if !__has_builtin(__builtin_amdgcn_cvt_pk_f32_fp8)
__device__ inline float e4m3dec(unsigned int v){
  int s = (v >> 7) & 1, e = (v >> 3) & 15, m = v & 7;
  float f = e ? ldexpf((float)(8 + m), e - 10) : ldexpf((float)m, -9);
  return s ? -f : f;
}
#endif

__device__ inline float dot8fp8(uint2 q, float4 hA, float4 hB, float acc){
#if __has_builtin(__builtin_amdgcn_cvt_pk_f32_fp8)
  f2v p0 = __builtin_amdgcn_cvt_pk_f32_fp8(q.x, false);
  f2v p1 = __builtin_amdgcn_cvt_pk_f32_fp8(q.x, true);
  f2v p2 = __builtin_amdgcn_cvt_pk_f32_fp8(q.y, false);
  f2v p3 = __builtin_amdgcn_cvt_pk_f32_fp8(q.y, true);
  acc += p0.x*hA.x + p0.y*hA.y + p1.x*hA.z + p1.y*hA.w;
  acc += p2.x*hB.x + p2.y*hB.y + p3.x*hB.z + p3.y*hB.w;
#else
  acc += e4m3dec(q.x & 255u)*hA.x + e4m3dec((q.x>>8)&255u)*hA.y
       + e4m3dec((q.x>>16)&255u)*hA.z + e4m3dec((q.x>>24)&255u)*hA.w;
  acc += e4m3dec(q.y & 255u)*hB.x + e4m3dec((q.y>>8)&255u)*hB.y
       + e4m3dec((q.y>>16)&255u)*hB.z + e4m3dec((q.y>>24)&255u)*hB.w;
#endif
  return acc;
}

__device__ inline float tanh_fast(float x){
  x = fminf(fmaxf(x, -20.f), 20.f);
  float e = __expf(-2.f * x);
  return (1.f - e) / (1.f + e);
}
__device__ inline float sigm(float x){
  return 1.f / (1.f + __expf(-x));
}

// ---------- workspace layout (bytes) ----------
constexpr size_t OFF_U    = 0;                              // bf16 [2][T][1024]
constexpr size_t SZ_U     = 2ull*TT*1024*2;
constexpr size_t OFF_X    = OFF_U + SZ_U;                   // bf16 [T][E]
constexpr size_t SZ_X     = (size_t)TT*EE*2;
constexpr size_t OFF_WIH  = OFF_X + SZ_X;                   // bf16 [2048][256]
constexpr size_t SZ_WIH   = 2048ull*256*2;
constexpr size_t OFF_BIAS = OFF_WIH + SZ_WIH;               // f32 [2048]
constexpr size_t SZ_BIAS  = 2048ull*4;
constexpr size_t OFF_WREG = OFF_BIAS + SZ_BIAS;             // f16 [2][50][512][8]
constexpr size_t SZ_WREG  = 2ull*50*512*8*2;
constexpr size_t OFF_WLDS = OFF_WREG + SZ_WREG;             // u8  [2][14][512][8]
constexpr size_t SZ_WLDS  = 2ull*14*512*8;
constexpr size_t OFF_HOUT = OFF_WLDS + SZ_WLDS;             // bf16 [T][512]
constexpr size_t SZ_HOUT  = (size_t)TT*512*2;
constexpr size_t OFF_FE   = OFF_HOUT + SZ_HOUT;             // f32 [T][20]
constexpr size_t SZ_FE    = (size_t)TT*LL*4;
constexpr size_t OFF_P    = OFF_FE + SZ_FE;                 // f32 [256][20][20]
constexpr size_t SZ_P     = 256ull*400*4;
constexpr size_t OFF_BAL  = OFF_P + SZ_P;                   // f32 [257][20]
constexpr size_t SZ_BAL   = 20736;                          // padded
constexpr size_t OFF_BP   = OFF_BAL + SZ_BAL;               // u8 [T][20]
constexpr size_t SZ_BP    = (size_t)TT*LL;
constexpr size_t OFF_M    = OFF_BP + SZ_BP;                 // u8 [256][20]
constexpr size_t SZ_M     = 256ull*LL;
constexpr size_t OFF_EG   = OFF_M + SZ_M + 64;              // i32 [256]

// ---------- kernels ----------

// gather: X_bf16[t][k] = bf16(emb[x[t]][k])
__global__ void k_gather(const int* __restrict__ x, const float* __restrict__ emb,
                         unsigned short* __restrict__ X){
  int t = blockIdx.x;
  int xt = x[t];
  const float4* src = (const float4*)(emb + (size_t)xt * EE);
  float4 v = src[threadIdx.x];
  ushort4 o;
  o.x = f2bf(v.x); o.y = f2bf(v.y); o.z = f2bf(v.z); o.w = f2bf(v.w);
  ((ushort4*)(X + (size_t)t * EE))[threadIdx.x] = o;
}

// concat + cast W_ih: WIH[2048][256] bf16 (rows 0..1023 fwd, 1024..2047 bwd)
__global__ void k_wih(const float* __restrict__ wf, const float* __restrict__ wb,
                      unsigned short* __restrict__ WIH){
  int gid = blockIdx.x * 256 + threadIdx.x;   // 65536
  int row = gid >> 5, c8 = gid & 31;
  const float* src = (row < 1024 ? wf + (size_t)row * EE : wb + (size_t)(row - 1024) * EE) + c8 * 8;
  unsigned short* dst = WIH + (size_t)row * 256 + c8 * 8;
#pragma unroll
  for (int i = 0; i < 8; i++) dst[i] = f2bf(src[i]);
}

__global__ void k_bias(const float* bf, const float* hf, const float* bb, const float* hb,
                       float* __restrict__ bias){
  int i = blockIdx.x * 256 + threadIdx.x;     // 2048
  int r = i & 1023;
  bias[i] = (i < 1024) ? (bf[r] + hf[r]) : (bb[r] + hb[r]);
}

// pack W_hh: per thread(t in 0..511): rows (t, 512+t).
// cols 0..199 -> f16 reg image WREG[d][ch 0..49][512][8]
// cols 200..255 -> fp8 LDS image WLDS[d][ch 0..13][512][8]
__global__ void k_whh(const float* __restrict__ whf, const float* __restrict__ whb,
                      _Float16* __restrict__ WREG, unsigned char* __restrict__ WLDS){
  int gid = blockIdx.x * 256 + threadIdx.x;   // 65536
  int d = gid >> 15;
  int rest = gid & 32767;
  int ch = rest >> 9;
  int tt = rest & 511;
  const float* W = d ? whb : whf;
  if (ch < 50){
    int rp = ch / 25, cc = ch % 25;
    int row = rp ? 512 + tt : tt;
    const float* s = W + (size_t)row * 256 + cc * 8;
    _Float16* dst = WREG + (((size_t)d * 50 + ch) * 512 + tt) * 8;
#pragma unroll
    for (int i = 0; i < 8; i++) dst[i] = (_Float16)s[i];
  } else {
    int lc = ch - 50;                     // 0..13
    int rp = lc / 7, cc = lc % 7;
    int row = rp ? 512 + tt : tt;
    const float* s = W + (size_t)row * 256 + 200 + cc * 8;
    unsigned char* dst = WLDS + (((size_t)d * 14 + lc) * 512 + tt) * 8;
#pragma unroll
    for (int i = 0; i < 8; i++) dst[i] = f2e4m3(s[i]);
  }
}

// U[d][t][r] = bf16( X[t]·WIH[r + d*1024] + bias )  via 16x16x32 bf16 MFMA
__global__ void k_gemm_u(const unsigned short* __restrict__ X,
                         const unsigned short* __restrict__ WIH,
                         const float* __restrict__ bias,
                         unsigned short* __restrict__ U){
  int wave = threadIdx.x >> 6, l = threadIdx.x & 63;
  int tile = blockIdx.x * 4 + wave;           // 0..32767
  int mt = tile & 255, nt = tile >> 8;        // 256 x 128 tiles
  int lm = l & 15, lq = l >> 4;
  const unsigned short* Arow = X   + (size_t)(mt * 16 + lm) * 256 + lq * 8;
  const unsigned short* Brow = WIH + (size_t)(nt * 16 + lm) * 256 + lq * 8;
  v4f acc = {0.f, 0.f, 0.f, 0.f};
#pragma unroll
  for (int kb = 0; kb < 8; kb++){
    v8s a = *(const v8s*)(Arow + kb * 32);
    v8s b = *(const v8s*)(Brow + kb * 32);
    acc = __builtin_amdgcn_mfma_f32_16x16x32_bf16(a, b, acc, 0, 0, 0);
  }
  int n = nt * 16 + lm;
  int d = n >> 10, r = n & 1023;
  float bi = bias[n];
#pragma unroll
  for (int r4 = 0; r4 < 4; r4++){
    int t = mt * 16 + lq * 4 + r4;
    U[((size_t)d * TT + t) * 1024 + r] = f2bf(acc[r4] + bi);
  }
}

// The recurrent core: grid=2 (dir), block=512. No inter-WG communication.
// thread owns gate rows (tid, 512+tid). cols 0..199 f16 in regs, 200..255 fp8 in LDS.
__global__ __launch_bounds__(512, 2) void k_lstm(
    const unsigned short* __restrict__ U, const _Float16* __restrict__ WREG,
    const unsigned char* __restrict__ WLDS, const float* __restrict__ h0,
    const float* __restrict__ c0, unsigned short* __restrict__ hout){
  int d = blockIdx.x;
  int tid = threadIdx.x;
  __shared__ __align__(16) unsigned char wl[14 * 512 * 8];   // 57344
  __shared__ __align__(16) float hf32[256];
  __shared__ __align__(16) _Float16 hf16[256];
  __shared__ __align__(16) float zbuf[1024];

  uint4 wr[50];
  const uint4* wsrc = (const uint4*)(WREG + (size_t)d * 50 * 512 * 8);
#pragma unroll
  for (int c = 0; c < 50; c++) wr[c] = wsrc[c * 512 + tid];

  const uint2* lsrc = (const uint2*)(WLDS + (size_t)d * 14 * 512 * 8);
  uint2* wl2 = (uint2*)wl;
#pragma unroll
  for (int c = 0; c < 14; c++) wl2[c * 512 + tid] = lsrc[c * 512 + tid];

  float c_state = 0.f;
  if (tid < 256){
    float h = h0[d * 256 + tid];
    c_state = c0[d * 256 + tid];
    hf32[tid] = h;
    hf16[tid] = (_Float16)h;
  }
  __syncthreads();

  const unsigned short* Ud = U + (size_t)d * TT * 1024;
  int stp = d ? -1 : 1;
  int tt0 = d ? TT - 1 : 0;
  unsigned short u0 = Ud[(size_t)tt0 * 1024 + tid];
  unsigned short u1 = Ud[(size_t)tt0 * 1024 + 512 + tid];

  for (int s = 0; s < TT; s++){
    int tt = d ? (TT - 1 - s) : s;
    float a0 = bf2f(u0), a1 = bf2f(u1);
    if (s + 1 < TT){
      int tn = tt + stp;
      u0 = Ud[(size_t)tn * 1024 + tid];
      u1 = Ud[(size_t)tn * 1024 + 512 + tid];
    }
    const uint4* hq = (const uint4*)hf16;
#pragma unroll
    for (int c = 0; c < 25; c++){
      uint4 hv = hq[c];
      h2 hA = as_h2(hv.x), hB = as_h2(hv.y), hC = as_h2(hv.z), hD = as_h2(hv.w);
      uint4 w0 = wr[c], w1 = wr[25 + c];
      a0 = FDOT2(as_h2(w0.x), hA, a0);
      a0 = FDOT2(as_h2(w0.y), hB, a0);
      a0 = FDOT2(as_h2(w0.z), hC, a0);
      a0 = FDOT2(as_h2(w0.w), hD, a0);
      a1 = FDOT2(as_h2(w1.x), hA, a1);
      a1 = FDOT2(as_h2(w1.y), hB, a1);
      a1 = FDOT2(as_h2(w1.z), hC, a1);
      a1 = FDOT2(as_h2(w1.w), hD, a1);
    }
    const float4* hfq = (const float4*)hf32;
#pragma unroll
    for (int c = 0; c < 7; c++){
      float4 hA4 = hfq[50 + 2 * c];
      float4 hB4 = hfq[51 + 2 * c];
      uint2 q0 = wl2[c * 512 + tid];
      uint2 q1 = wl2[(7 + c) * 512 + tid];
      a0 = dot8fp8(q0, hA4, hB4, a0);
      a1 = dot8fp8(q1, hA4, hB4, a1);
    }
    zbuf[tid] = a0;
    zbuf[512 + tid] = a1;
    __syncthreads();
    if (tid < 256){
      float zi = zbuf[tid], zf = zbuf[256 + tid], zg = zbuf[512 + tid], zo = zbuf[768 + tid];
      float gi = sigm(zi), gf = sigm(zf), go = sigm(zo), gg = tanh_fast(zg);
      c_state = gf * c_state + gi * gg;
      float h = go * tanh_fast(c_state);
      hout[(size_t)tt * 512 + (d << 8) + tid] = f2bf(h);
      hf32[tid] = h;
      hf16[tid] = (_Float16)h;
    }
    __syncthreads();
  }
}

// feats[t][j] = hout[t]·w_out[j] + b_out[j]
__global__ void k_feats(const unsigned short* __restrict__ hout,
                        const float* __restrict__ wout, const float* __restrict__ bout,
                        float* __restrict__ feats){
  int t = blockIdx.x, j = threadIdx.x;
  if (j >= LL) return;
  const unsigned short* h = hout + (size_t)t * 512;
  const float* w = wout + (size_t)j * 512;
  float acc = bout[j];
#pragma unroll 8
  for (int k = 0; k < 512; k++) acc = fmaf(bf2f(h[k]), w[k], acc);
  feats[t * LL + j] = acc;
}

// V1: per-chunk max-plus matrix product P_c (16 steps folded onto identity)
__global__ void k_vchunk(const float* __restrict__ feats, const float* __restrict__ trans,
                         float* __restrict__ P){
  int c = blockIdx.x, j = threadIdx.x;
  __shared__ float Ps[2][LL][LL];
  bool act = j < LL;
  float trow[LL];
  if (act){
#pragma unroll
    for (int i = 0; i < LL; i++) trow[i] = trans[j * LL + i];
    for (int i = 0; i < LL; i++) Ps[0][i][j] = (i == j) ? 0.f : -1e30f;
  }
  __syncthreads();
  for (int s = 0; s < 16; s++){
    int t = c * 16 + s;
    int pb = s & 1;
    if (act){
      float fj = feats[t * LL + j];
      for (int i = 0; i < LL; i++){
        float m = Ps[pb][i][0] + trow[0];
#pragma unroll
        for (int mm = 1; mm < LL; mm++) m = fmaxf(m, Ps[pb][i][mm] + trow[mm]);
        Ps[pb ^ 1][i][j] = m + fj;
      }
    }
    __syncthreads();
  }
  if (act)
    for (int i = 0; i < LL; i++) P[((size_t)c * LL + i) * LL + j] = Ps[0][i][j];
}

// V2: sequential boundary-alpha scan over 256 chunk matrices
__global__ void k_vscan(const float* __restrict__ P, float* __restrict__ bal){
  int tid = threadIdx.x;
  bool act = tid < LL;
  __shared__ float al[LL];
  __shared__ float Pl[LL * LL];
  if (act){
    float a = (tid == STARTT) ? 0.f : NEGV;
    al[tid] = a;
    bal[tid] = a;
  }
  __syncthreads();
  for (int c = 0; c < NCH; c++){
    for (int k = tid; k < LL * LL; k += 64) Pl[k] = P[(size_t)c * 400 + k];
    __syncthreads();
    float m = -1e30f;
    if (act){
      m = al[0] + Pl[tid];
#pragma unroll
      for (int i = 1; i < LL; i++) m = fmaxf(m, al[i] + Pl[i * LL + tid]);
    }
    __syncthreads();
    if (act){
      al[tid] = m;
      bal[(c + 1) * LL + tid] = m;
    }
    __syncthreads();
  }
}

// V3: per-chunk backpointers + chunk backtrace map M_c
__global__ void k_vbp(const float* __restrict__ feats, const float* __restrict__ trans,
                      const float* __restrict__ bal, unsigned char* __restrict__ bp,
                      unsigned char* __restrict__ M){
  int c = blockIdx.x, j = threadIdx.x;
  bool act = j < LL;
  __shared__ float al[2][LL];
  __shared__ unsigned char bpl[16][LL];
  float trow[LL];
  if (act){
#pragma unroll
    for (int i = 0; i < LL; i++) trow[i] = trans[j * LL + i];
    al[0][j] = bal[c * LL + j];
  }
  __syncthreads();
  for (int s = 0; s < 16; s++){
    int t = c * 16 + s;
    int pb = s & 1;
    if (act){
      float m = al[pb][0] + trow[0];
      int arg = 0;
#pragma unroll
      for (int i = 1; i < LL; i++){
        float v = al[pb][i] + trow[i];
        if (v > m){ m = v; arg = i; }
      }
      bpl[s][j] = (unsigned char)arg;
      bp[(size_t)t * LL + j] = (unsigned char)arg;
      al[pb ^ 1][j] = m + feats[t * LL + j];
    }
    __syncthreads();
  }
  if (act){
    int tag = j;
    for (int s = 15; s >= 0; s--) tag = bpl[s][tag];
    M[c * LL + j] = (unsigned char)tag;
  }
}

// V4: final score + sequential chunk-boundary tag chase
__global__ void k_vtag(const float* __restrict__ bal, const float* __restrict__ trans,
                       const unsigned char* __restrict__ M, int* __restrict__ Eg,
                       float* __restrict__ out){
  int tid = threadIdx.x;
  __shared__ unsigned char Ml[NCH * LL];
  __shared__ float fin[LL];
  for (int k = tid; k < NCH * LL; k += 64) Ml[k] = M[k];
  if (tid < LL) fin[tid] = bal[NCH * LL + tid] + trans[STOPP * LL + tid];
  __syncthreads();
  if (tid == 0){
    float m = fin[0]; int arg = 0;
    for (int i = 1; i < LL; i++) if (fin[i] > m){ m = fin[i]; arg = i; }
    out[0] = m;
    int tag = arg;
    Eg[NCH - 1] = tag;
    for (int c = NCH - 1; c >= 1; c--){
      tag = Ml[c * LL + tag];
      Eg[c - 1] = tag;
    }
  }
}

// V5: parallel path emission (one chunk per thread)
__global__ void k_vemit(const int* __restrict__ Eg, const unsigned char* __restrict__ bp,
                        float* __restrict__ out){
  int c = threadIdx.x;
  int tag = Eg[c];
  out[1 + c * 16 + 15] = (float)tag;
  for (int s = 15; s >= 1; s--){
    tag = bp[(size_t)(c * 16 + s) * LL + tag];
    out[1 + c * 16 + s - 1] = (float)tag;
  }
}

// ---------- launcher ----------
extern "C" void kernel_launch(void* const* d_in, const int* in_sizes, int n_in,
                              void* d_out, int out_size, void* d_ws, size_t ws_size,
                              hipStream_t stream){
  (void)in_sizes; (void)n_in; (void)out_size; (void)ws_size;
  const int*   x     = (const int*)d_in[0];
  const float* emb   = (const float*)d_in[1];
  const float* wihf  = (const float*)d_in[2];
  const float* whhf  = (const float*)d_in[3];
  const float* bihf  = (const float*)d_in[4];
  const float* bhhf  = (const float*)d_in[5];
  const float* wihb  = (const float*)d_in[6];
  const float* whhb  = (const float*)d_in[7];
  const float* bihb  = (const float*)d_in[8];
  const float* bhhb  = (const float*)d_in[9];
  const float* wout  = (const float*)d_in[10];
  const float* bout  = (const float*)d_in[11];
  const float* trans = (const float*)d_in[12];
  const float* h0    = (const float*)d_in[13];
  const float* c0    = (const float*)d_in[14];
  float* out = (float*)d_out;
  char* ws = (char*)d_ws;

  unsigned short* U    = (unsigned short*)(ws + OFF_U);
  unsigned short* X    = (unsigned short*)(ws + OFF_X);
  unsigned short* WIH  = (unsigned short*)(ws + OFF_WIH);
  float*          BIAS = (float*)(ws + OFF_BIAS);
  _Float16*       WREG = (_Float16*)(ws + OFF_WREG);
  unsigned char*  WLDS = (unsigned char*)(ws + OFF_WLDS);
  unsigned short* HOUT = (unsigned short*)(ws + OFF_HOUT);
  float*          FE   = (float*)(ws + OFF_FE);
  float*          P    = (float*)(ws + OFF_P);
  float*          BAL  = (float*)(ws + OFF_BAL);
  unsigned char*  BP   = (unsigned char*)(ws + OFF_BP);
  unsigned char*  M    = (unsigned char*)(ws + OFF_M);
  int*            EG   = (int*)(ws + OFF_EG);

  k_gather<<<TT, 64, 0, stream>>>(x, emb, X);
  k_wih<<<256, 256, 0, stream>>>(wihf, wihb, WIH);
  k_bias<<<8, 256, 0, stream>>>(bihf, bhhf, bihb, bhhb, BIAS);
  k_whh<<<256, 256, 0, stream>>>(whhf, whhb, WREG, WLDS);
  k_gemm_u<<<8192, 256, 0, stream>>>(X, WIH, BIAS, U);
  k_lstm<<<2, 512, 0, stream>>>(U, WREG, WLDS, h0, c0, HOUT);
  k_feats<<<TT, 64, 0, stream>>>(HOUT, wout, bout, FE);
  k_vchunk<<<NCH, 64, 0, stream>>>(FE, trans, P);
  k_vscan<<<1, 64, 0, stream>>>(P, BAL);
  k_vbp<<<NCH, 64, 0, stream>>>(FE, trans, BAL, BP, M);
  k_vtag<<<1, 64, 0, stream>>>(BAL, trans, M, EG, out);
  k_vemit<<<1, 256, 0, stream>>>(EG, BP, out);
}